// Round 10
// baseline (289.860 us; speedup 1.0000x reference)
//
#include <hip/hip_runtime.h>
#include <hip/hip_bf16.h>

// VQ-VAE pipeline. Round 10: (a) quant argmin re-done in registers as packed
// sortable-u32 (ord(score)&~511 | code) held in a u32x16 ext-vector -> kills
// the LDS scoreboard (131k ds ops + 16 barriers/block) that round 6 added to
// dodge round-5's scalar-array spill; (b) fin_kernel folded into convt3_loss
// via device-scope ticket (1-block launch = ~5us serial time). Top-5 is now
// the harness's 268MB ws-poison fill (43us @ 77% HBM) - not ours.

#define NB 16
#define T0 32768
#define T1 16384
#define T2 8192
#define T3 4096
#define NCODES 512
#define EDIM 64

typedef __attribute__((ext_vector_type(8)))  short short8;
typedef __attribute__((ext_vector_type(16))) float f32x16;
typedef __attribute__((ext_vector_type(16))) unsigned u32x16;
typedef __attribute__((ext_vector_type(4)))  float f32x4;

__device__ __forceinline__ float b2f(short s) {
    unsigned u = ((unsigned)(unsigned short)s) << 16;
    float f; __builtin_memcpy(&f, &u, 4); return f;
}
__device__ __forceinline__ short f2bs(float f) {
    __hip_bfloat16 h = __float2bfloat16(f);
    short s; __builtin_memcpy(&s, &h, 2); return s;
}
// monotone float -> sortable unsigned
__device__ __forceinline__ unsigned f2ord(float s) {
    unsigned u = __float_as_uint(s);
    return u ^ ((unsigned)((int)u >> 31) | 0x80000000u);
}

__device__ __forceinline__ float block_sum256(float v) {
    #pragma unroll
    for (int off = 32; off > 0; off >>= 1) v += __shfl_down(v, off, 64);
    __shared__ float red[4];
    int lane = threadIdx.x & 63, wv = threadIdx.x >> 6;
    if (lane == 0) red[wv] = v;
    __syncthreads();
    return red[0] + red[1] + red[2] + red[3];
}

// ---------------- conv1 via MFMA im2col: K = tap*8+ic (56, padded 64) -------
__global__ __launch_bounds__(256, 2)
void conv1_mfma(const float* __restrict__ x, const short* __restrict__ w1b,
                const float* __restrict__ b1, short* __restrict__ y) {
    constexpr int BT = 128, NR = 262;
    __shared__ short lxc[NR * 8];
    __shared__ short lw[64 * 64];
    int tid = threadIdx.x, b = blockIdx.z, t0 = blockIdx.x * BT;
    for (int i = tid; i < 512; i += 256) {
        int oc = i >> 3, c8 = i & 7;
        short8 v = *(const short8*)(w1b + oc * 64 + c8 * 8);
        *(short8*)(lw + oc * 64 + (c8 ^ (oc & 7)) * 8) = v;
    }
    for (int r = tid; r < NR; r += 256) {
        int g = 2 * t0 - 3 + r;
        short8 p;
        bool ok = (unsigned)g < (unsigned)T0;
        #pragma unroll
        for (int ic = 0; ic < 8; ic++) {
            float v = ok ? x[((size_t)b * 8 + ic) * T0 + g] : 0.f;
            p[ic] = f2bs(v);
        }
        *(short8*)(lxc + r * 8) = p;
    }
    __syncthreads();
    int wv = tid >> 6, lane = tid & 63, lm = lane & 31, lk = lane >> 5;
    int ml = wv * 32 + lm;
    f32x16 acc[2];
    #pragma unroll
    for (int oj = 0; oj < 2; oj++)
        #pragma unroll
        for (int r = 0; r < 16; r++) acc[oj][r] = 0.f;
    #pragma unroll
    for (int kc = 0; kc < 4; kc++) {
        int q = kc * 2 + lk;
        short8 a = *(const short8*)(lxc + (2 * ml + q) * 8);
        #pragma unroll
        for (int oj = 0; oj < 2; oj++) {
            int oc = oj * 32 + lm;
            short8 bf = *(const short8*)(lw + oc * 64 + (q ^ (oc & 7)) * 8);
            acc[oj] = __builtin_amdgcn_mfma_f32_32x32x16_bf16(a, bf, acc[oj], 0, 0, 0);
        }
    }
    #pragma unroll
    for (int oj = 0; oj < 2; oj++) {
        int oc = oj * 32 + lm;
        float bs = b1[oc];
        #pragma unroll
        for (int r = 0; r < 16; r++) {
            int t = t0 + wv * 32 + (r & 3) + 8 * (r >> 2) + 4 * lk;
            float v = fmaxf(acc[oj][r] + bs, 0.f);
            y[((size_t)b * T1 + t) * 64 + oc] = f2bs(v);
        }
    }
}

// --------- MFMA forward conv, weights in LDS, oc-split ----------------------
template<int IC, int OC, int OCB, int TAPS, int PAD, int BT, int NW, bool RELU, bool F32OUT>
__global__ __launch_bounds__(NW * 64, 2)
void conv_mfma_fwd(const short* __restrict__ x, const short* __restrict__ wb,
                   const float* __restrict__ bias, void* __restrict__ yout,
                   int Tin, int Tout) {
    constexpr int C8 = IC / 8;
    constexpr int NR = 2 * (BT - 1) + TAPS;
    __shared__ short lw[TAPS * OCB * IC];
    __shared__ short lx[NR * IC];
    const int tid = threadIdx.x;
    const int b   = blockIdx.z;
    const int ocg = blockIdx.y * OCB;
    const int t0  = blockIdx.x * BT;
    const int r0  = 2 * t0 - PAD;
    for (int i = tid; i < TAPS * OCB * C8; i += NW * 64) {
        int tap = i / (OCB * C8), rem = i - tap * OCB * C8;
        int ocl = rem / C8, c8 = rem - ocl * C8;
        short8 v = *(const short8*)(wb + ((size_t)tap * OC + ocg + ocl) * IC + c8 * 8);
        *(short8*)(lw + (tap * OCB + ocl) * IC + (c8 ^ (ocl & (C8 - 1))) * 8) = v;
    }
    const short* xg = x + (size_t)b * Tin * IC;
    short8 zz = {0, 0, 0, 0, 0, 0, 0, 0};
    for (int idx = tid; idx < NR * C8; idx += NW * 64) {
        int row = idx / C8, c8 = idx - row * C8;
        int gr = r0 + row;
        short8 v = zz;
        if ((unsigned)gr < (unsigned)Tin)
            v = *(const short8*)(xg + (size_t)gr * IC + c8 * 8);
        *(short8*)(lx + row * IC + (c8 ^ ((row >> 1) & (C8 - 1))) * 8) = v;
    }
    __syncthreads();

    const int wv = tid >> 6, lane = tid & 63;
    const int tl = wv * 32;
    const int lm = lane & 31, lk = lane >> 5;
    f32x16 acc[OCB / 32];
    #pragma unroll
    for (int oj = 0; oj < OCB / 32; oj++)
        #pragma unroll
        for (int r = 0; r < 16; r++) acc[oj][r] = 0.f;

    #pragma unroll
    for (int tap = 0; tap < TAPS; tap++) {
        #pragma unroll
        for (int kc = 0; kc < IC / 16; kc++) {
            int row = 2 * (tl + lm) + tap;
            int c8  = kc * 2 + lk;
            short8 a = *(const short8*)(lx + row * IC + (c8 ^ ((row >> 1) & (C8 - 1))) * 8);
            #pragma unroll
            for (int oj = 0; oj < OCB / 32; oj++) {
                int ocl = oj * 32 + lm;
                short8 bf = *(const short8*)(lw + (tap * OCB + ocl) * IC +
                                             (c8 ^ (ocl & (C8 - 1))) * 8);
                acc[oj] = __builtin_amdgcn_mfma_f32_32x32x16_bf16(a, bf, acc[oj], 0, 0, 0);
            }
        }
    }
    #pragma unroll
    for (int oj = 0; oj < OCB / 32; oj++) {
        int oc = ocg + oj * 32 + lm;
        float bs = bias[oc];
        #pragma unroll
        for (int r = 0; r < 16; r++) {
            int t = t0 + tl + (r & 3) + 8 * (r >> 2) + 4 * lk;
            float v = acc[oj][r] + bs;
            if (RELU) v = fmaxf(v, 0.f);
            if (F32OUT)
                ((float*)yout)[((size_t)b * Tout + t) * OC + oc] = v;
            else
                ((short*)yout)[((size_t)b * Tout + t) * OC + oc] = f2bs(v);
        }
    }
}

// --------- MFMA conv-transpose (k4 s2 p1), weights in LDS, oc-split ---------
template<int IC, int OC, int OCB, int BT, int NW, bool RELU>
__global__ __launch_bounds__(NW * 64, 2)
void conv_mfma_t(const short* __restrict__ x, const short* __restrict__ wb,
                 const float* __restrict__ bias, short* __restrict__ y, int Tin) {
    constexpr int C8 = IC / 8;
    constexpr int NR = BT + 2;
    __shared__ short lw[4 * OCB * IC];
    __shared__ short lx[NR * IC];
    const int tid = threadIdx.x;
    const int b   = blockIdx.z;
    const int ocg = blockIdx.y * OCB;
    const int m0  = blockIdx.x * BT;
    const int r0  = m0 - 1;
    for (int i = tid; i < 4 * OCB * C8; i += NW * 64) {
        int k = i / (OCB * C8), rem = i - k * OCB * C8;
        int ocl = rem / C8, c8 = rem - ocl * C8;
        short8 v = *(const short8*)(wb + ((size_t)k * OC + ocg + ocl) * IC + c8 * 8);
        *(short8*)(lw + (k * OCB + ocl) * IC + (c8 ^ (ocl & (C8 - 1))) * 8) = v;
    }
    const short* xg = x + (size_t)b * Tin * IC;
    short8 zz = {0, 0, 0, 0, 0, 0, 0, 0};
    for (int idx = tid; idx < NR * C8; idx += NW * 64) {
        int row = idx / C8, c8 = idx - row * C8;
        int gr = r0 + row;
        short8 v = zz;
        if ((unsigned)gr < (unsigned)Tin)
            v = *(const short8*)(xg + (size_t)gr * IC + c8 * 8);
        *(short8*)(lx + row * IC + (c8 ^ ((row >> 1) & (C8 - 1))) * 8) = v;
    }
    __syncthreads();

    const int wv = tid >> 6, lane = tid & 63;
    const int ml = wv * 32;
    const int lm = lane & 31, lk = lane >> 5;
    f32x16 accE[OCB / 32], accO[OCB / 32];
    #pragma unroll
    for (int oj = 0; oj < OCB / 32; oj++)
        #pragma unroll
        for (int r = 0; r < 16; r++) { accE[oj][r] = 0.f; accO[oj][r] = 0.f; }

    #pragma unroll
    for (int kc = 0; kc < IC / 16; kc++) {
        int c8 = kc * 2 + lk;
        int rA = ml + lm;
        short8 a_m1, a_0, a_p1;
        {
            int row = rA;
            a_m1 = *(const short8*)(lx + row * IC + (c8 ^ ((row >> 1) & (C8 - 1))) * 8);
            row = rA + 1;
            a_0  = *(const short8*)(lx + row * IC + (c8 ^ ((row >> 1) & (C8 - 1))) * 8);
            row = rA + 2;
            a_p1 = *(const short8*)(lx + row * IC + (c8 ^ ((row >> 1) & (C8 - 1))) * 8);
        }
        #pragma unroll
        for (int oj = 0; oj < OCB / 32; oj++) {
            int ocl = oj * 32 + lm;
            int sw = (c8 ^ (ocl & (C8 - 1))) * 8;
            short8 w0 = *(const short8*)(lw + ((0 * OCB + ocl) * IC) + sw);
            short8 w1 = *(const short8*)(lw + ((1 * OCB + ocl) * IC) + sw);
            short8 w2 = *(const short8*)(lw + ((2 * OCB + ocl) * IC) + sw);
            short8 w3 = *(const short8*)(lw + ((3 * OCB + ocl) * IC) + sw);
            accE[oj] = __builtin_amdgcn_mfma_f32_32x32x16_bf16(a_0,  w1, accE[oj], 0, 0, 0);
            accE[oj] = __builtin_amdgcn_mfma_f32_32x32x16_bf16(a_m1, w3, accE[oj], 0, 0, 0);
            accO[oj] = __builtin_amdgcn_mfma_f32_32x32x16_bf16(a_p1, w0, accO[oj], 0, 0, 0);
            accO[oj] = __builtin_amdgcn_mfma_f32_32x32x16_bf16(a_0,  w2, accO[oj], 0, 0, 0);
        }
    }
    int Tout = 2 * Tin;
    #pragma unroll
    for (int oj = 0; oj < OCB / 32; oj++) {
        int oc = ocg + oj * 32 + lm;
        float bs = bias[oc];
        #pragma unroll
        for (int r = 0; r < 16; r++) {
            int m = m0 + ml + (r & 3) + 8 * (r >> 2) + 4 * lk;
            float ve = accE[oj][r] + bs;
            float vo = accO[oj][r] + bs;
            if (RELU) { ve = fmaxf(ve, 0.f); vo = fmaxf(vo, 0.f); }
            short* yp = y + ((size_t)b * Tout + 2 * m) * OC + oc;
            yp[0]  = f2bs(ve);
            yp[OC] = f2bs(vo);
        }
    }
}

// ---- convT3 (64->8) + recon MSE via MFMA im2col, fin folded via ticket -----
__global__ __launch_bounds__(256, 2)
void convt3_loss(const short* __restrict__ r2, const short* __restrict__ w3m,
                 const float* __restrict__ db3, const float* __restrict__ x,
                 float* __restrict__ acc, const float* __restrict__ cnd,
                 float* __restrict__ out) {
    constexpr int BT = 256, NR = 258;
    constexpr int NBLK = (T1 / BT) * NB;
    __shared__ short lr[NR * 64];
    __shared__ short lw[16 * 200];
    __shared__ float lxt[8 * 512];
    __shared__ unsigned lastFlag;
    int tid = threadIdx.x, b = blockIdx.z, m0 = blockIdx.x * BT;
    for (int i = tid; i < 384; i += 256) {
        int n = i / 24, kc = i - n * 24;
        *(short8*)(lw + n * 200 + kc * 8) = *(const short8*)(w3m + n * 192 + kc * 8);
    }
    const short* rb = r2 + (size_t)b * T1 * 64;
    short8 zz = {0, 0, 0, 0, 0, 0, 0, 0};
    for (int i = tid; i < NR * 8; i += 256) {
        int r = i >> 3, c8 = i & 7;
        int g = m0 - 1 + r;
        short8 v = zz;
        if ((unsigned)g < (unsigned)T1)
            v = *(const short8*)(rb + (size_t)g * 64 + c8 * 8);
        *(short8*)(lr + r * 64 + (c8 ^ (r & 7)) * 8) = v;
    }
    const float* xb = x + (size_t)b * 8 * T0;
    for (int i = tid; i < 1024; i += 256) {
        int oc = i >> 7, c4 = (i & 127) * 4;
        *(float4*)(lxt + oc * 512 + c4) =
            *(const float4*)(xb + (size_t)oc * T0 + 2 * m0 + c4);
    }
    __syncthreads();
    int wv = tid >> 6, lane = tid & 63;
    int row16 = lane & 15, quad = lane >> 4;
    short8 bfr[6];
    #pragma unroll
    for (int kb = 0; kb < 6; kb++)
        bfr[kb] = *(const short8*)(lw + row16 * 200 + kb * 32 + quad * 8);
    f32x4 accv[4];
    #pragma unroll
    for (int rg = 0; rg < 4; rg++) accv[rg] = (f32x4){0.f, 0.f, 0.f, 0.f};
    #pragma unroll
    for (int kb = 0; kb < 6; kb++) {
        int kg = kb * 32 + quad * 8;
        int ro = kg >> 6, c8 = (kg >> 3) & 7;
        #pragma unroll
        for (int rg = 0; rg < 4; rg++) {
            int r = wv * 64 + rg * 16 + row16 + ro;
            short8 a = *(const short8*)(lr + r * 64 + (c8 ^ (r & 7)) * 8);
            accv[rg] = __builtin_amdgcn_mfma_f32_16x16x32_bf16(a, bfr[kb], accv[rg], 0, 0, 0);
        }
    }
    int oc = row16 & 7, par = row16 >> 3;
    float bs = db3[oc];
    float s = 0.f;
    #pragma unroll
    for (int rg = 0; rg < 4; rg++)
        #pragma unroll
        for (int reg = 0; reg < 4; reg++) {
            int ml = wv * 64 + rg * 16 + quad * 4 + reg;
            float v = accv[rg][reg] + bs;
            float d = v - lxt[oc * 512 + 2 * ml + par];
            s += d * d;
        }
    s = block_sum256(s);
    if (tid == 0) {
        atomicAdd(acc + 1, s);
        __threadfence();
        unsigned old = atomicAdd((unsigned*)(acc + 2), 1u);
        lastFlag = (old == NBLK - 1) ? 1u : 0u;
    }
    __syncthreads();
    if (lastFlag) {   // last block finalizes all outputs (fin_kernel folded in)
        for (int i = tid; i < 1024; i += 256)
            out[i] = cnd[i] * (1.f / (float)T3);
        if (tid == 0) {
            float vq = acc[0] * (1.f / 4194304.f);          // quant kernel: done
            float rl = atomicAdd(acc + 1, 0.f);             // coherent read
            out[1024] = vq;
            out[1025] = vq;
            out[1026] = rl * (1.f / 4194304.f);
        }
    }
}

// -------- prep: accumulators, codebook norms+bf16, weight transposes --------
__global__ void prep_kernel(const float* __restrict__ cb, const float* __restrict__ w1,
                            const float* __restrict__ w2, const float* __restrict__ w3,
                            const float* __restrict__ dw1, const float* __restrict__ dw2,
                            const float* __restrict__ dw3,
                            float* __restrict__ c2, float* __restrict__ cond,
                            float* __restrict__ acc,
                            short* __restrict__ wb2, short* __restrict__ wb3,
                            short* __restrict__ wT1, short* __restrict__ wT2,
                            short* __restrict__ cbbf, short* __restrict__ w1b,
                            short* __restrict__ w3m) {
    int i = blockIdx.x * 256 + threadIdx.x;
    if (i < 8) acc[i] = 0.f;
    if (i < 1024) cond[i] = 0.f;
    if (i < NCODES) {
        float s = 0.f;
        #pragma unroll
        for (int d = 0; d < EDIM; d++) { float v = cb[i * EDIM + d]; s += v * v; }
        c2[i] = s;
    }
    if (i < 32768) cbbf[i] = f2bs(cb[i]);      // [c][d] bf16
    if (i < 4096) {                            // w1b[oc][k], k=tap*8+ic, pad 0
        int oc = i >> 6, k = i & 63;
        int ic = k & 7, q = k >> 3;
        w1b[i] = (q < 7) ? f2bs(w1[((size_t)oc * 8 + ic) * 7 + q]) : (short)0;
    }
    if (i < 3072) {                            // w3m[n][k], K=192 im2col B
        int n = i / 192, k = i - (i / 192) * 192;
        int oc = n & 7;
        float v = 0.f;
        if (n < 8) {
            if (k < 64)       v = dw3[((size_t)k * 8 + oc) * 4 + 3];
            else if (k < 128) v = dw3[((size_t)(k - 64) * 8 + oc) * 4 + 1];
        } else {
            if (k >= 128)     v = dw3[((size_t)(k - 128) * 8 + oc) * 4 + 0];
            else if (k >= 64) v = dw3[((size_t)(k - 64) * 8 + oc) * 4 + 2];
        }
        w3m[i] = f2bs(v);
    }
    if (i < 40960) {
        int tap = i / 8192, r = i - tap * 8192;
        int oc = r >> 6, ic = r & 63;
        wb2[i] = f2bs(w2[((size_t)oc * 64 + ic) * 5 + tap]);
    }
    if (i < 24576) {
        int tap = i / 8192, r = i - tap * 8192;
        int oc = r >> 7, ic = r & 127;
        wb3[i] = f2bs(w3[((size_t)oc * 128 + ic) * 3 + tap]);
    }
    if (i < 32768) {
        int k = i / 8192, r = i - k * 8192;
        int oc = r >> 6, ic = r & 63;
        wT1[i] = f2bs(dw1[((size_t)ic * 128 + oc) * 4 + k]);
    }
    if (i < 32768) {
        int k = i / 8192, r = i - k * 8192;
        int oc = r >> 7, ic = r & 127;
        wT2[i] = f2bs(dw2[((size_t)ic * 64 + oc) * 4 + k]);
    }
}

// -------- VQ via MFMA + packed sortable-u32 register argmin -----------------
// packed = ord(score) & ~511 | code: min() = (score, then first-index) argmin.
__global__ __launch_bounds__(256, 4)
void quant_kernel(const float* __restrict__ ze, const float* __restrict__ cb,
                  const short* __restrict__ cbbf, const float* __restrict__ c2g,
                  short* __restrict__ zq, float* __restrict__ cond,
                  float* __restrict__ acc) {
    __shared__ short lx[128 * 64];
    __shared__ int   ibuf[128];
    __shared__ float cscr[1024];
    __shared__ float lc2[NCODES];
    int tid = threadIdx.x;
    int bb = blockIdx.x >> 5;
    int t0 = (blockIdx.x & 31) * 128;
    const float* zrow = ze + ((size_t)(bb * T3 + t0)) * 64;
    for (int i = tid; i < NCODES; i += 256) lc2[i] = c2g[i];
    for (int task = tid; task < 1024; task += 256) {
        int row = task >> 3, c8 = task & 7;
        const float4* s = (const float4*)(zrow + row * 64 + c8 * 8);
        float4 v0 = s[0], v1 = s[1];
        short8 p;
        p[0] = f2bs(v0.x); p[1] = f2bs(v0.y); p[2] = f2bs(v0.z); p[3] = f2bs(v0.w);
        p[4] = f2bs(v1.x); p[5] = f2bs(v1.y); p[6] = f2bs(v1.z); p[7] = f2bs(v1.w);
        *(short8*)(lx + row * 64 + (c8 ^ (row & 7)) * 8) = p;
    }
    __syncthreads();
    int wv = tid >> 6, lane = tid & 63, lm = lane & 31, lk = lane >> 5;
    short8 afr[4];
    int arow = wv * 32 + lm;
    #pragma unroll
    for (int kc = 0; kc < 4; kc++) {
        int c8 = kc * 2 + lk;
        afr[kc] = *(const short8*)(lx + arow * 64 + (c8 ^ (arow & 7)) * 8);
    }
    u32x16 bestp;
    #pragma unroll
    for (int r = 0; r < 16; r++) bestp[r] = 0xFFFFFFFFu;
    for (int ct = 0; ct < 16; ct++) {
        f32x16 a;
        #pragma unroll
        for (int r = 0; r < 16; r++) a[r] = 0.f;
        const short* wg = cbbf + ((size_t)(ct * 32 + lm)) * 64 + lk * 8;
        #pragma unroll
        for (int kc = 0; kc < 4; kc++) {
            short8 bf = *(const short8*)(wg + kc * 16);
            a = __builtin_amdgcn_mfma_f32_32x32x16_bf16(afr[kc], bf, a, 0, 0, 0);
        }
        unsigned cidx = (unsigned)(ct * 32 + lm);
        float c2v = lc2[cidx];
        #pragma unroll
        for (int r = 0; r < 16; r++) {
            float s = c2v - 2.f * a[r];
            unsigned p = (f2ord(s) & 0xFFFFFE00u) | cidx;
            bestp[r] = (p < bestp[r]) ? p : bestp[r];
        }
    }
    // cross-lane min over the 32 lm-lanes (lk halves reduce independently)
    #pragma unroll
    for (int r = 0; r < 16; r++) {
        unsigned p = bestp[r];
        #pragma unroll
        for (int mk = 1; mk < 32; mk <<= 1) {
            unsigned op = (unsigned)__shfl_xor((int)p, mk, 64);
            p = (op < p) ? op : p;
        }
        if (lm == 0) ibuf[wv * 32 + (r & 3) + 8 * (r >> 2) + 4 * lk] = (int)(p & 511u);
    }
    __syncthreads();
    float vql = 0.f;
    {
        int t = tid >> 1, dh = (tid & 1) * 32;
        int code = ibuf[t];
        const float4* cv = (const float4*)(cb + (size_t)code * 64 + dh);
        const float4* zv = (const float4*)(zrow + (size_t)t * 64 + dh);
        short* zqp = zq + ((size_t)(bb * T3 + t0 + t)) * 64 + dh;
        #pragma unroll
        for (int q = 0; q < 4; q++) {
            float4 c0v = cv[2 * q], c1v = cv[2 * q + 1];
            float4 z0 = zv[2 * q], z1 = zv[2 * q + 1];
            float d;
            d = z0.x - c0v.x; vql += d * d;
            d = z0.y - c0v.y; vql += d * d;
            d = z0.z - c0v.z; vql += d * d;
            d = z0.w - c0v.w; vql += d * d;
            d = z1.x - c1v.x; vql += d * d;
            d = z1.y - c1v.y; vql += d * d;
            d = z1.z - c1v.z; vql += d * d;
            d = z1.w - c1v.w; vql += d * d;
            short8 p;
            p[0] = f2bs(c0v.x); p[1] = f2bs(c0v.y); p[2] = f2bs(c0v.z); p[3] = f2bs(c0v.w);
            p[4] = f2bs(c1v.x); p[5] = f2bs(c1v.y); p[6] = f2bs(c1v.z); p[7] = f2bs(c1v.w);
            *(short8*)(zqp + q * 8) = p;
        }
    }
    {
        int d4 = (tid & 15) * 4;
        int g  = tid >> 4;
        float4 s4 = {0.f, 0.f, 0.f, 0.f};
        for (int t = g; t < 128; t += 16) {
            float4 v = *(const float4*)(cb + (size_t)ibuf[t] * 64 + d4);
            s4.x += v.x; s4.y += v.y; s4.z += v.z; s4.w += v.w;
        }
        *(float4*)(cscr + g * 64 + d4) = s4;
        __syncthreads();
        if (tid < 64) {
            float s = 0.f;
            #pragma unroll
            for (int g2 = 0; g2 < 16; g2++) s += cscr[g2 * 64 + tid];
            atomicAdd(cond + bb * 64 + tid, s);
        }
    }
    vql = block_sum256(vql);
    if (tid == 0) atomicAdd(acc, vql);
}

extern "C" void kernel_launch(void* const* d_in, const int* in_sizes, int n_in,
                              void* d_out, int out_size, void* d_ws, size_t ws_size,
                              hipStream_t stream) {
    const float* x   = (const float*)d_in[0];
    const float* w1  = (const float*)d_in[1];
    const float* b1  = (const float*)d_in[2];
    const float* w2  = (const float*)d_in[3];
    const float* b2  = (const float*)d_in[4];
    const float* w3  = (const float*)d_in[5];
    const float* b3  = (const float*)d_in[6];
    const float* cb  = (const float*)d_in[7];
    const float* dw1 = (const float*)d_in[8];
    const float* db1 = (const float*)d_in[9];
    const float* dw2 = (const float*)d_in[10];
    const float* db2 = (const float*)d_in[11];
    const float* dw3 = (const float*)d_in[12];
    const float* db3 = (const float*)d_in[13];
    float* out = (float*)d_out;

    char* ws = (char*)d_ws;
    short* a1   = (short*)(ws);                    // [16][16384][64] bf16; later r2
    short* a2   = (short*)(ws + 33554432);         // [16][8192][128] bf16; later r1
    float* ze   = (float*)(ws + 67108864);         // [16][4096][64] fp32
    short* zq   = (short*)(ws + 83886080);         // [16][4096][64] bf16
    short* wb2  = (short*)(ws + 92274688);
    short* wb3  = (short*)(ws + 92356608);
    short* wT1  = (short*)(ws + 92405760);
    short* wT2  = (short*)(ws + 92471296);
    short* cbbf = (short*)(ws + 92536832);         // [512][64] bf16
    short* w1b  = (short*)(ws + 92602368);         // [64][64] bf16 (conv1 im2col)
    short* w3m  = (short*)(ws + 92610560);         // [16][192] bf16 (convt3 im2col)
    float* c2   = (float*)(ws + 92616704);
    float* cnd  = (float*)(ws + 92618752);
    float* acc  = (float*)(ws + 92622848);

    prep_kernel<<<160, 256, 0, stream>>>(cb, w1, w2, w3, dw1, dw2, dw3, c2, cnd,
                                         acc, wb2, wb3, wT1, wT2, cbbf, w1b, w3m);
    conv1_mfma<<<dim3(T1 / 128, 1, NB), 256, 0, stream>>>(x, w1b, b1, a1);
    conv_mfma_fwd<64, 128, 64, 5, 2, 128, 4, true, false>
        <<<dim3(T2 / 128, 2, NB), 256, 0, stream>>>(a1, wb2, b2, a2, T1, T2);
    conv_mfma_fwd<128, 64, 32, 3, 1, 64, 2, false, true>
        <<<dim3(T3 / 64, 2, NB), 128, 0, stream>>>(a2, wb3, b3, ze, T2, T3);
    quant_kernel<<<NB * (T3 / 128), 256, 0, stream>>>(ze, cb, cbbf, c2, zq, cnd, acc);
    conv_mfma_t<64, 128, 64, 128, 4, true>
        <<<dim3(T3 / 128, 2, NB), 256, 0, stream>>>(zq, wT1, db1, a2, T3);
    conv_mfma_t<128, 64, 32, 128, 4, true>
        <<<dim3(T2 / 128, 2, NB), 256, 0, stream>>>(a2, wT2, db2, a1, T2);
    convt3_loss<<<dim3(T1 / 256, 1, NB), 256, 0, stream>>>(a1, w3m, db3, x, acc,
                                                           cnd, out);
}

// Round 11
// 274.751 us; speedup vs baseline: 1.0550x; 1.0550x over previous
//
#include <hip/hip_runtime.h>
#include <hip/hip_bf16.h>

// VQ-VAE pipeline. Round 11: isolate round-10's regression (275->290us).
// Keep packed sortable-u32 register argmin in quant (ord(score)&~511|code,
// u32x16 state, no LDS scoreboard / no per-ct barriers) but at the PROVEN
// __launch_bounds__(256,2) (round-10's (256,4) risked a VGPR-cap spill).
// Revert the convt3 ticket fold (its per-block __threadfence = L2 inv x1024
// blocks); fin_kernel is a separate launch again, as in round 9 (275us).

#define NB 16
#define T0 32768
#define T1 16384
#define T2 8192
#define T3 4096
#define NCODES 512
#define EDIM 64

typedef __attribute__((ext_vector_type(8)))  short short8;
typedef __attribute__((ext_vector_type(16))) float f32x16;
typedef __attribute__((ext_vector_type(16))) unsigned u32x16;
typedef __attribute__((ext_vector_type(4)))  float f32x4;

__device__ __forceinline__ float b2f(short s) {
    unsigned u = ((unsigned)(unsigned short)s) << 16;
    float f; __builtin_memcpy(&f, &u, 4); return f;
}
__device__ __forceinline__ short f2bs(float f) {
    __hip_bfloat16 h = __float2bfloat16(f);
    short s; __builtin_memcpy(&s, &h, 2); return s;
}
// monotone float -> sortable unsigned
__device__ __forceinline__ unsigned f2ord(float s) {
    unsigned u = __float_as_uint(s);
    return u ^ ((unsigned)((int)u >> 31) | 0x80000000u);
}

__device__ __forceinline__ float block_sum256(float v) {
    #pragma unroll
    for (int off = 32; off > 0; off >>= 1) v += __shfl_down(v, off, 64);
    __shared__ float red[4];
    int lane = threadIdx.x & 63, wv = threadIdx.x >> 6;
    if (lane == 0) red[wv] = v;
    __syncthreads();
    return red[0] + red[1] + red[2] + red[3];
}

// ---------------- conv1 via MFMA im2col: K = tap*8+ic (56, padded 64) -------
__global__ __launch_bounds__(256, 2)
void conv1_mfma(const float* __restrict__ x, const short* __restrict__ w1b,
                const float* __restrict__ b1, short* __restrict__ y) {
    constexpr int BT = 128, NR = 262;
    __shared__ short lxc[NR * 8];
    __shared__ short lw[64 * 64];
    int tid = threadIdx.x, b = blockIdx.z, t0 = blockIdx.x * BT;
    for (int i = tid; i < 512; i += 256) {
        int oc = i >> 3, c8 = i & 7;
        short8 v = *(const short8*)(w1b + oc * 64 + c8 * 8);
        *(short8*)(lw + oc * 64 + (c8 ^ (oc & 7)) * 8) = v;
    }
    for (int r = tid; r < NR; r += 256) {
        int g = 2 * t0 - 3 + r;
        short8 p;
        bool ok = (unsigned)g < (unsigned)T0;
        #pragma unroll
        for (int ic = 0; ic < 8; ic++) {
            float v = ok ? x[((size_t)b * 8 + ic) * T0 + g] : 0.f;
            p[ic] = f2bs(v);
        }
        *(short8*)(lxc + r * 8) = p;
    }
    __syncthreads();
    int wv = tid >> 6, lane = tid & 63, lm = lane & 31, lk = lane >> 5;
    int ml = wv * 32 + lm;
    f32x16 acc[2];
    #pragma unroll
    for (int oj = 0; oj < 2; oj++)
        #pragma unroll
        for (int r = 0; r < 16; r++) acc[oj][r] = 0.f;
    #pragma unroll
    for (int kc = 0; kc < 4; kc++) {
        int q = kc * 2 + lk;
        short8 a = *(const short8*)(lxc + (2 * ml + q) * 8);
        #pragma unroll
        for (int oj = 0; oj < 2; oj++) {
            int oc = oj * 32 + lm;
            short8 bf = *(const short8*)(lw + oc * 64 + (q ^ (oc & 7)) * 8);
            acc[oj] = __builtin_amdgcn_mfma_f32_32x32x16_bf16(a, bf, acc[oj], 0, 0, 0);
        }
    }
    #pragma unroll
    for (int oj = 0; oj < 2; oj++) {
        int oc = oj * 32 + lm;
        float bs = b1[oc];
        #pragma unroll
        for (int r = 0; r < 16; r++) {
            int t = t0 + wv * 32 + (r & 3) + 8 * (r >> 2) + 4 * lk;
            float v = fmaxf(acc[oj][r] + bs, 0.f);
            y[((size_t)b * T1 + t) * 64 + oc] = f2bs(v);
        }
    }
}

// --------- MFMA forward conv, weights in LDS, oc-split ----------------------
template<int IC, int OC, int OCB, int TAPS, int PAD, int BT, int NW, bool RELU, bool F32OUT>
__global__ __launch_bounds__(NW * 64, 2)
void conv_mfma_fwd(const short* __restrict__ x, const short* __restrict__ wb,
                   const float* __restrict__ bias, void* __restrict__ yout,
                   int Tin, int Tout) {
    constexpr int C8 = IC / 8;
    constexpr int NR = 2 * (BT - 1) + TAPS;
    __shared__ short lw[TAPS * OCB * IC];
    __shared__ short lx[NR * IC];
    const int tid = threadIdx.x;
    const int b   = blockIdx.z;
    const int ocg = blockIdx.y * OCB;
    const int t0  = blockIdx.x * BT;
    const int r0  = 2 * t0 - PAD;
    for (int i = tid; i < TAPS * OCB * C8; i += NW * 64) {
        int tap = i / (OCB * C8), rem = i - tap * OCB * C8;
        int ocl = rem / C8, c8 = rem - ocl * C8;
        short8 v = *(const short8*)(wb + ((size_t)tap * OC + ocg + ocl) * IC + c8 * 8);
        *(short8*)(lw + (tap * OCB + ocl) * IC + (c8 ^ (ocl & (C8 - 1))) * 8) = v;
    }
    const short* xg = x + (size_t)b * Tin * IC;
    short8 zz = {0, 0, 0, 0, 0, 0, 0, 0};
    for (int idx = tid; idx < NR * C8; idx += NW * 64) {
        int row = idx / C8, c8 = idx - row * C8;
        int gr = r0 + row;
        short8 v = zz;
        if ((unsigned)gr < (unsigned)Tin)
            v = *(const short8*)(xg + (size_t)gr * IC + c8 * 8);
        *(short8*)(lx + row * IC + (c8 ^ ((row >> 1) & (C8 - 1))) * 8) = v;
    }
    __syncthreads();

    const int wv = tid >> 6, lane = tid & 63;
    const int tl = wv * 32;
    const int lm = lane & 31, lk = lane >> 5;
    f32x16 acc[OCB / 32];
    #pragma unroll
    for (int oj = 0; oj < OCB / 32; oj++)
        #pragma unroll
        for (int r = 0; r < 16; r++) acc[oj][r] = 0.f;

    #pragma unroll
    for (int tap = 0; tap < TAPS; tap++) {
        #pragma unroll
        for (int kc = 0; kc < IC / 16; kc++) {
            int row = 2 * (tl + lm) + tap;
            int c8  = kc * 2 + lk;
            short8 a = *(const short8*)(lx + row * IC + (c8 ^ ((row >> 1) & (C8 - 1))) * 8);
            #pragma unroll
            for (int oj = 0; oj < OCB / 32; oj++) {
                int ocl = oj * 32 + lm;
                short8 bf = *(const short8*)(lw + (tap * OCB + ocl) * IC +
                                             (c8 ^ (ocl & (C8 - 1))) * 8);
                acc[oj] = __builtin_amdgcn_mfma_f32_32x32x16_bf16(a, bf, acc[oj], 0, 0, 0);
            }
        }
    }
    #pragma unroll
    for (int oj = 0; oj < OCB / 32; oj++) {
        int oc = ocg + oj * 32 + lm;
        float bs = bias[oc];
        #pragma unroll
        for (int r = 0; r < 16; r++) {
            int t = t0 + tl + (r & 3) + 8 * (r >> 2) + 4 * lk;
            float v = acc[oj][r] + bs;
            if (RELU) v = fmaxf(v, 0.f);
            if (F32OUT)
                ((float*)yout)[((size_t)b * Tout + t) * OC + oc] = v;
            else
                ((short*)yout)[((size_t)b * Tout + t) * OC + oc] = f2bs(v);
        }
    }
}

// --------- MFMA conv-transpose (k4 s2 p1), weights in LDS, oc-split ---------
template<int IC, int OC, int OCB, int BT, int NW, bool RELU>
__global__ __launch_bounds__(NW * 64, 2)
void conv_mfma_t(const short* __restrict__ x, const short* __restrict__ wb,
                 const float* __restrict__ bias, short* __restrict__ y, int Tin) {
    constexpr int C8 = IC / 8;
    constexpr int NR = BT + 2;
    __shared__ short lw[4 * OCB * IC];
    __shared__ short lx[NR * IC];
    const int tid = threadIdx.x;
    const int b   = blockIdx.z;
    const int ocg = blockIdx.y * OCB;
    const int m0  = blockIdx.x * BT;
    const int r0  = m0 - 1;
    for (int i = tid; i < 4 * OCB * C8; i += NW * 64) {
        int k = i / (OCB * C8), rem = i - k * OCB * C8;
        int ocl = rem / C8, c8 = rem - ocl * C8;
        short8 v = *(const short8*)(wb + ((size_t)k * OC + ocg + ocl) * IC + c8 * 8);
        *(short8*)(lw + (k * OCB + ocl) * IC + (c8 ^ (ocl & (C8 - 1))) * 8) = v;
    }
    const short* xg = x + (size_t)b * Tin * IC;
    short8 zz = {0, 0, 0, 0, 0, 0, 0, 0};
    for (int idx = tid; idx < NR * C8; idx += NW * 64) {
        int row = idx / C8, c8 = idx - row * C8;
        int gr = r0 + row;
        short8 v = zz;
        if ((unsigned)gr < (unsigned)Tin)
            v = *(const short8*)(xg + (size_t)gr * IC + c8 * 8);
        *(short8*)(lx + row * IC + (c8 ^ ((row >> 1) & (C8 - 1))) * 8) = v;
    }
    __syncthreads();

    const int wv = tid >> 6, lane = tid & 63;
    const int ml = wv * 32;
    const int lm = lane & 31, lk = lane >> 5;
    f32x16 accE[OCB / 32], accO[OCB / 32];
    #pragma unroll
    for (int oj = 0; oj < OCB / 32; oj++)
        #pragma unroll
        for (int r = 0; r < 16; r++) { accE[oj][r] = 0.f; accO[oj][r] = 0.f; }

    #pragma unroll
    for (int kc = 0; kc < IC / 16; kc++) {
        int c8 = kc * 2 + lk;
        int rA = ml + lm;
        short8 a_m1, a_0, a_p1;
        {
            int row = rA;
            a_m1 = *(const short8*)(lx + row * IC + (c8 ^ ((row >> 1) & (C8 - 1))) * 8);
            row = rA + 1;
            a_0  = *(const short8*)(lx + row * IC + (c8 ^ ((row >> 1) & (C8 - 1))) * 8);
            row = rA + 2;
            a_p1 = *(const short8*)(lx + row * IC + (c8 ^ ((row >> 1) & (C8 - 1))) * 8);
        }
        #pragma unroll
        for (int oj = 0; oj < OCB / 32; oj++) {
            int ocl = oj * 32 + lm;
            int sw = (c8 ^ (ocl & (C8 - 1))) * 8;
            short8 w0 = *(const short8*)(lw + ((0 * OCB + ocl) * IC) + sw);
            short8 w1 = *(const short8*)(lw + ((1 * OCB + ocl) * IC) + sw);
            short8 w2 = *(const short8*)(lw + ((2 * OCB + ocl) * IC) + sw);
            short8 w3 = *(const short8*)(lw + ((3 * OCB + ocl) * IC) + sw);
            accE[oj] = __builtin_amdgcn_mfma_f32_32x32x16_bf16(a_0,  w1, accE[oj], 0, 0, 0);
            accE[oj] = __builtin_amdgcn_mfma_f32_32x32x16_bf16(a_m1, w3, accE[oj], 0, 0, 0);
            accO[oj] = __builtin_amdgcn_mfma_f32_32x32x16_bf16(a_p1, w0, accO[oj], 0, 0, 0);
            accO[oj] = __builtin_amdgcn_mfma_f32_32x32x16_bf16(a_0,  w2, accO[oj], 0, 0, 0);
        }
    }
    int Tout = 2 * Tin;
    #pragma unroll
    for (int oj = 0; oj < OCB / 32; oj++) {
        int oc = ocg + oj * 32 + lm;
        float bs = bias[oc];
        #pragma unroll
        for (int r = 0; r < 16; r++) {
            int m = m0 + ml + (r & 3) + 8 * (r >> 2) + 4 * lk;
            float ve = accE[oj][r] + bs;
            float vo = accO[oj][r] + bs;
            if (RELU) { ve = fmaxf(ve, 0.f); vo = fmaxf(vo, 0.f); }
            short* yp = y + ((size_t)b * Tout + 2 * m) * OC + oc;
            yp[0]  = f2bs(ve);
            yp[OC] = f2bs(vo);
        }
    }
}

// ---- convT3 (64->8) + recon MSE via 16x16x32 MFMA im2col (K=192), BT=256 ---
__global__ __launch_bounds__(256, 2)
void convt3_loss(const short* __restrict__ r2, const short* __restrict__ w3m,
                 const float* __restrict__ db3, const float* __restrict__ x,
                 float* __restrict__ acc) {
    constexpr int BT = 256, NR = 258;
    __shared__ short lr[NR * 64];      // rows m0-1..m0+256, slot c8 ^= (r&7)
    __shared__ short lw[16 * 200];     // [n][k], stride 200
    __shared__ float lxt[8 * 512];     // x[oc][2*m0 .. 2*m0+511]
    int tid = threadIdx.x, b = blockIdx.z, m0 = blockIdx.x * BT;
    for (int i = tid; i < 384; i += 256) {
        int n = i / 24, kc = i - n * 24;
        *(short8*)(lw + n * 200 + kc * 8) = *(const short8*)(w3m + n * 192 + kc * 8);
    }
    const short* rb = r2 + (size_t)b * T1 * 64;
    short8 zz = {0, 0, 0, 0, 0, 0, 0, 0};
    for (int i = tid; i < NR * 8; i += 256) {
        int r = i >> 3, c8 = i & 7;
        int g = m0 - 1 + r;
        short8 v = zz;
        if ((unsigned)g < (unsigned)T1)
            v = *(const short8*)(rb + (size_t)g * 64 + c8 * 8);
        *(short8*)(lr + r * 64 + (c8 ^ (r & 7)) * 8) = v;
    }
    const float* xb = x + (size_t)b * 8 * T0;
    for (int i = tid; i < 1024; i += 256) {
        int oc = i >> 7, c4 = (i & 127) * 4;
        *(float4*)(lxt + oc * 512 + c4) =
            *(const float4*)(xb + (size_t)oc * T0 + 2 * m0 + c4);
    }
    __syncthreads();
    int wv = tid >> 6, lane = tid & 63;
    int row16 = lane & 15, quad = lane >> 4;
    short8 bfr[6];
    #pragma unroll
    for (int kb = 0; kb < 6; kb++)
        bfr[kb] = *(const short8*)(lw + row16 * 200 + kb * 32 + quad * 8);
    f32x4 accv[4];
    #pragma unroll
    for (int rg = 0; rg < 4; rg++) accv[rg] = (f32x4){0.f, 0.f, 0.f, 0.f};
    #pragma unroll
    for (int kb = 0; kb < 6; kb++) {
        int kg = kb * 32 + quad * 8;
        int ro = kg >> 6, c8 = (kg >> 3) & 7;
        #pragma unroll
        for (int rg = 0; rg < 4; rg++) {     // 4 independent MFMA chains
            int r = wv * 64 + rg * 16 + row16 + ro;
            short8 a = *(const short8*)(lr + r * 64 + (c8 ^ (r & 7)) * 8);
            accv[rg] = __builtin_amdgcn_mfma_f32_16x16x32_bf16(a, bfr[kb], accv[rg], 0, 0, 0);
        }
    }
    int oc = row16 & 7, par = row16 >> 3;
    float bs = db3[oc];
    float s = 0.f;
    #pragma unroll
    for (int rg = 0; rg < 4; rg++)
        #pragma unroll
        for (int reg = 0; reg < 4; reg++) {
            int ml = wv * 64 + rg * 16 + quad * 4 + reg;
            float v = accv[rg][reg] + bs;
            float d = v - lxt[oc * 512 + 2 * ml + par];
            s += d * d;
        }
    s = block_sum256(s);
    if (tid == 0) atomicAdd(acc + 1, s);
}

// -------- prep: accumulators, codebook norms+bf16, weight transposes --------
__global__ void prep_kernel(const float* __restrict__ cb, const float* __restrict__ w1,
                            const float* __restrict__ w2, const float* __restrict__ w3,
                            const float* __restrict__ dw1, const float* __restrict__ dw2,
                            const float* __restrict__ dw3,
                            float* __restrict__ c2, float* __restrict__ cond,
                            float* __restrict__ acc,
                            short* __restrict__ wb2, short* __restrict__ wb3,
                            short* __restrict__ wT1, short* __restrict__ wT2,
                            short* __restrict__ cbbf, short* __restrict__ w1b,
                            short* __restrict__ w3m) {
    int i = blockIdx.x * 256 + threadIdx.x;
    if (i < 8) acc[i] = 0.f;
    if (i < 1024) cond[i] = 0.f;
    if (i < NCODES) {
        float s = 0.f;
        #pragma unroll
        for (int d = 0; d < EDIM; d++) { float v = cb[i * EDIM + d]; s += v * v; }
        c2[i] = s;
    }
    if (i < 32768) cbbf[i] = f2bs(cb[i]);      // [c][d] bf16
    if (i < 4096) {                            // w1b[oc][k], k=tap*8+ic, pad 0
        int oc = i >> 6, k = i & 63;
        int ic = k & 7, q = k >> 3;
        w1b[i] = (q < 7) ? f2bs(w1[((size_t)oc * 8 + ic) * 7 + q]) : (short)0;
    }
    if (i < 3072) {                            // w3m[n][k], K=192 im2col B
        int n = i / 192, k = i - (i / 192) * 192;
        int oc = n & 7;
        float v = 0.f;
        if (n < 8) {
            if (k < 64)       v = dw3[((size_t)k * 8 + oc) * 4 + 3];
            else if (k < 128) v = dw3[((size_t)(k - 64) * 8 + oc) * 4 + 1];
        } else {
            if (k >= 128)     v = dw3[((size_t)(k - 128) * 8 + oc) * 4 + 0];
            else if (k >= 64) v = dw3[((size_t)(k - 64) * 8 + oc) * 4 + 2];
        }
        w3m[i] = f2bs(v);
    }
    if (i < 40960) {
        int tap = i / 8192, r = i - tap * 8192;
        int oc = r >> 6, ic = r & 63;
        wb2[i] = f2bs(w2[((size_t)oc * 64 + ic) * 5 + tap]);
    }
    if (i < 24576) {
        int tap = i / 8192, r = i - tap * 8192;
        int oc = r >> 7, ic = r & 127;
        wb3[i] = f2bs(w3[((size_t)oc * 128 + ic) * 3 + tap]);
    }
    if (i < 32768) {
        int k = i / 8192, r = i - k * 8192;
        int oc = r >> 6, ic = r & 63;
        wT1[i] = f2bs(dw1[((size_t)ic * 128 + oc) * 4 + k]);
    }
    if (i < 32768) {
        int k = i / 8192, r = i - k * 8192;
        int oc = r >> 7, ic = r & 127;
        wT2[i] = f2bs(dw2[((size_t)ic * 64 + oc) * 4 + k]);
    }
}

// -------- VQ via MFMA + packed sortable-u32 register argmin -----------------
// packed = ord(score) & ~511 | code: min() = (score, then first-index) argmin.
__global__ __launch_bounds__(256, 2)
void quant_kernel(const float* __restrict__ ze, const float* __restrict__ cb,
                  const short* __restrict__ cbbf, const float* __restrict__ c2g,
                  short* __restrict__ zq, float* __restrict__ cond,
                  float* __restrict__ acc) {
    __shared__ short lx[128 * 64];
    __shared__ int   ibuf[128];
    __shared__ float cscr[1024];
    __shared__ float lc2[NCODES];
    int tid = threadIdx.x;
    int bb = blockIdx.x >> 5;
    int t0 = (blockIdx.x & 31) * 128;
    const float* zrow = ze + ((size_t)(bb * T3 + t0)) * 64;
    for (int i = tid; i < NCODES; i += 256) lc2[i] = c2g[i];
    for (int task = tid; task < 1024; task += 256) {
        int row = task >> 3, c8 = task & 7;
        const float4* s = (const float4*)(zrow + row * 64 + c8 * 8);
        float4 v0 = s[0], v1 = s[1];
        short8 p;
        p[0] = f2bs(v0.x); p[1] = f2bs(v0.y); p[2] = f2bs(v0.z); p[3] = f2bs(v0.w);
        p[4] = f2bs(v1.x); p[5] = f2bs(v1.y); p[6] = f2bs(v1.z); p[7] = f2bs(v1.w);
        *(short8*)(lx + row * 64 + (c8 ^ (row & 7)) * 8) = p;
    }
    __syncthreads();
    int wv = tid >> 6, lane = tid & 63, lm = lane & 31, lk = lane >> 5;
    short8 afr[4];
    int arow = wv * 32 + lm;
    #pragma unroll
    for (int kc = 0; kc < 4; kc++) {
        int c8 = kc * 2 + lk;
        afr[kc] = *(const short8*)(lx + arow * 64 + (c8 ^ (arow & 7)) * 8);
    }
    u32x16 bestp;
    #pragma unroll
    for (int r = 0; r < 16; r++) bestp[r] = 0xFFFFFFFFu;
    for (int ct = 0; ct < 16; ct++) {
        f32x16 a;
        #pragma unroll
        for (int r = 0; r < 16; r++) a[r] = 0.f;
        const short* wg = cbbf + ((size_t)(ct * 32 + lm)) * 64 + lk * 8;
        #pragma unroll
        for (int kc = 0; kc < 4; kc++) {
            short8 bf = *(const short8*)(wg + kc * 16);
            a = __builtin_amdgcn_mfma_f32_32x32x16_bf16(afr[kc], bf, a, 0, 0, 0);
        }
        unsigned cidx = (unsigned)(ct * 32 + lm);
        float c2v = lc2[cidx];
        #pragma unroll
        for (int r = 0; r < 16; r++) {
            float s = c2v - 2.f * a[r];
            unsigned p = (f2ord(s) & 0xFFFFFE00u) | cidx;
            bestp[r] = (p < bestp[r]) ? p : bestp[r];
        }
    }
    // cross-lane min over the 32 lm-lanes (lk halves reduce independently)
    #pragma unroll
    for (int r = 0; r < 16; r++) {
        unsigned p = bestp[r];
        #pragma unroll
        for (int mk = 1; mk < 32; mk <<= 1) {
            unsigned op = (unsigned)__shfl_xor((int)p, mk, 64);
            p = (op < p) ? op : p;
        }
        if (lm == 0) ibuf[wv * 32 + (r & 3) + 8 * (r >> 2) + 4 * lk] = (int)(p & 511u);
    }
    __syncthreads();
    float vql = 0.f;
    {
        int t = tid >> 1, dh = (tid & 1) * 32;
        int code = ibuf[t];
        const float4* cv = (const float4*)(cb + (size_t)code * 64 + dh);
        const float4* zv = (const float4*)(zrow + (size_t)t * 64 + dh);
        short* zqp = zq + ((size_t)(bb * T3 + t0 + t)) * 64 + dh;
        #pragma unroll
        for (int q = 0; q < 4; q++) {
            float4 c0v = cv[2 * q], c1v = cv[2 * q + 1];
            float4 z0 = zv[2 * q], z1 = zv[2 * q + 1];
            float d;
            d = z0.x - c0v.x; vql += d * d;
            d = z0.y - c0v.y; vql += d * d;
            d = z0.z - c0v.z; vql += d * d;
            d = z0.w - c0v.w; vql += d * d;
            d = z1.x - c1v.x; vql += d * d;
            d = z1.y - c1v.y; vql += d * d;
            d = z1.z - c1v.z; vql += d * d;
            d = z1.w - c1v.w; vql += d * d;
            short8 p;
            p[0] = f2bs(c0v.x); p[1] = f2bs(c0v.y); p[2] = f2bs(c0v.z); p[3] = f2bs(c0v.w);
            p[4] = f2bs(c1v.x); p[5] = f2bs(c1v.y); p[6] = f2bs(c1v.z); p[7] = f2bs(c1v.w);
            *(short8*)(zqp + q * 8) = p;
        }
    }
    {
        int d4 = (tid & 15) * 4;
        int g  = tid >> 4;
        float4 s4 = {0.f, 0.f, 0.f, 0.f};
        for (int t = g; t < 128; t += 16) {
            float4 v = *(const float4*)(cb + (size_t)ibuf[t] * 64 + d4);
            s4.x += v.x; s4.y += v.y; s4.z += v.z; s4.w += v.w;
        }
        *(float4*)(cscr + g * 64 + d4) = s4;
        __syncthreads();
        if (tid < 64) {
            float s = 0.f;
            #pragma unroll
            for (int g2 = 0; g2 < 16; g2++) s += cscr[g2 * 64 + tid];
            atomicAdd(cond + bb * 64 + tid, s);
        }
    }
    vql = block_sum256(vql);
    if (tid == 0) atomicAdd(acc, vql);
}

__global__ void fin_kernel(const float* __restrict__ cond,
                           const float* __restrict__ acc, float* __restrict__ out) {
    int i = threadIdx.x;   // 1024 threads
    out[i] = cond[i] * (1.f / (float)T3);
    if (i == 0) {
        float vq = acc[0] * (1.f / 4194304.f);   // B*D*T3
        out[1024] = vq;
        out[1025] = vq;
        out[1026] = acc[1] * (1.f / 4194304.f);  // B*C0*T0
    }
}

extern "C" void kernel_launch(void* const* d_in, const int* in_sizes, int n_in,
                              void* d_out, int out_size, void* d_ws, size_t ws_size,
                              hipStream_t stream) {
    const float* x   = (const float*)d_in[0];
    const float* w1  = (const float*)d_in[1];
    const float* b1  = (const float*)d_in[2];
    const float* w2  = (const float*)d_in[3];
    const float* b2  = (const float*)d_in[4];
    const float* w3  = (const float*)d_in[5];
    const float* b3  = (const float*)d_in[6];
    const float* cb  = (const float*)d_in[7];
    const float* dw1 = (const float*)d_in[8];
    const float* db1 = (const float*)d_in[9];
    const float* dw2 = (const float*)d_in[10];
    const float* db2 = (const float*)d_in[11];
    const float* dw3 = (const float*)d_in[12];
    const float* db3 = (const float*)d_in[13];
    float* out = (float*)d_out;

    char* ws = (char*)d_ws;
    short* a1   = (short*)(ws);                    // [16][16384][64] bf16; later r2
    short* a2   = (short*)(ws + 33554432);         // [16][8192][128] bf16; later r1
    float* ze   = (float*)(ws + 67108864);         // [16][4096][64] fp32
    short* zq   = (short*)(ws + 83886080);         // [16][4096][64] bf16
    short* wb2  = (short*)(ws + 92274688);
    short* wb3  = (short*)(ws + 92356608);
    short* wT1  = (short*)(ws + 92405760);
    short* wT2  = (short*)(ws + 92471296);
    short* cbbf = (short*)(ws + 92536832);         // [512][64] bf16
    short* w1b  = (short*)(ws + 92602368);         // [64][64] bf16 (conv1 im2col)
    short* w3m  = (short*)(ws + 92610560);         // [16][192] bf16 (convt3 im2col)
    float* c2   = (float*)(ws + 92616704);
    float* cnd  = (float*)(ws + 92618752);
    float* acc  = (float*)(ws + 92622848);

    prep_kernel<<<160, 256, 0, stream>>>(cb, w1, w2, w3, dw1, dw2, dw3, c2, cnd,
                                         acc, wb2, wb3, wT1, wT2, cbbf, w1b, w3m);
    conv1_mfma<<<dim3(T1 / 128, 1, NB), 256, 0, stream>>>(x, w1b, b1, a1);
    conv_mfma_fwd<64, 128, 64, 5, 2, 128, 4, true, false>
        <<<dim3(T2 / 128, 2, NB), 256, 0, stream>>>(a1, wb2, b2, a2, T1, T2);
    conv_mfma_fwd<128, 64, 32, 3, 1, 64, 2, false, true>
        <<<dim3(T3 / 64, 2, NB), 128, 0, stream>>>(a2, wb3, b3, ze, T2, T3);
    quant_kernel<<<NB * (T3 / 128), 256, 0, stream>>>(ze, cb, cbbf, c2, zq, cnd, acc);
    conv_mfma_t<64, 128, 64, 128, 4, true>
        <<<dim3(T3 / 128, 2, NB), 256, 0, stream>>>(zq, wT1, db1, a2, T3);
    conv_mfma_t<128, 64, 32, 128, 4, true>
        <<<dim3(T2 / 128, 2, NB), 256, 0, stream>>>(a2, wT2, db2, a1, T2);
    convt3_loss<<<dim3(T1 / 256, 1, NB), 256, 0, stream>>>(a1, w3m, db3, x, acc);
    fin_kernel<<<1, 1024, 0, stream>>>(cnd, acc, out);
}